// Round 7
// baseline (1050.406 us; speedup 1.0000x reference)
//
#include <hip/hip_runtime.h>
#include <hip/hip_bf16.h>
#include <math.h>

#define VOCAB 32000
#define EMB   256
#define TSEQ  1024
#define NROWS 4096
#define NBLKN 250   // VOCAB/128

typedef __attribute__((ext_vector_type(8))) short short8;
typedef __attribute__((ext_vector_type(4))) float f32x4;

static __device__ __forceinline__ unsigned short bfb(float x) {
    __hip_bfloat16 h = __float2bfloat16(x);
    return *(unsigned short*)&h;
}
static __device__ __forceinline__ unsigned pk2(float a, float b) {
    return (unsigned)bfb(a) | ((unsigned)bfb(b) << 16);
}

// ---------------- embed: xb = bf16(tok_table[idx] + pos_table[t]) ----------------
__global__ __launch_bounds__(256) void k_embed(const int* __restrict__ idx,
                                               const float* __restrict__ tok,
                                               const float* __restrict__ pos,
                                               ushort* __restrict__ xb) {
    int row = blockIdx.x;
    int t = row & (TSEQ - 1);
    int token = idx[row];
    int e = threadIdx.x;
    xb[row * EMB + e] = bfb(tok[token * EMB + e] + pos[t * EMB + e]);
}

// ---------------- transpose+convert: lm_W (x<1000) and Wq/Wk/Wv (x>=1000) ----------------
__global__ __launch_bounds__(256) void k_conv(const float* __restrict__ lmW,
                                              const float* __restrict__ Wq,
                                              const float* __restrict__ Wk,
                                              const float* __restrict__ Wv,
                                              ushort* __restrict__ Wt,
                                              ushort* __restrict__ Wt3) {
    __shared__ float T[32][33];
    int bx = blockIdx.x, by = blockIdx.y;
    const float* W; ushort* out; int n0, k0, ncols;
    if (bx < 1000) {
        W = lmW; out = Wt; n0 = bx * 32; k0 = by * 32; ncols = VOCAB;
    } else {
        int xi = bx - 1000;          // 0..23
        int z = xi >> 3;
        W = (z == 0) ? Wq : (z == 1) ? Wk : Wv;
        out = Wt3 + (size_t)z * EMB * EMB;
        n0 = (xi & 7) * 32; k0 = by * 32; ncols = EMB;
    }
    int tx = threadIdx.x & 31, ty = threadIdx.x >> 5;
    #pragma unroll
    for (int i = 0; i < 4; ++i) {
        int kk = ty + 8 * i;
        T[kk][tx] = W[(size_t)(k0 + kk) * ncols + n0 + tx];
    }
    __syncthreads();
    #pragma unroll
    for (int i = 0; i < 4; ++i) {
        int r = ty + 8 * i;
        out[(size_t)(n0 + r) * EMB + k0 + tx] = bfb(T[tx][r]);
    }
}

// ---------------- qkv MFMA GEMM: q/k row-major bf16; v written transposed (vt) ----------------
__global__ __launch_bounds__(256) void k_qkv_mm(const ushort* __restrict__ A,
                                                const ushort* __restrict__ Wt3,
                                                ushort* __restrict__ qb,
                                                ushort* __restrict__ kbf,
                                                ushort* __restrict__ vt) {
    __shared__ ushort As[128 * 64];
    __shared__ ushort Bs[128 * 64];

    int z = blockIdx.z;
    const ushort* Bt = Wt3 + (size_t)z * EMB * EMB;

    int m0 = blockIdx.x * 128, n0 = blockIdx.y * 128;
    int tid = threadIdx.x;
    int lane = tid & 63, wave = tid >> 6;
    int wm = wave >> 1, wn = wave & 1;
    int lr = lane >> 3, cc = lane & 7;
    int lrow = lane & 15, lk = lane >> 4;

    f32x4 acc[4][4];
    #pragma unroll
    for (int i = 0; i < 4; ++i)
        #pragma unroll
        for (int j = 0; j < 4; ++j)
            acc[i][j] = (f32x4){0.f, 0.f, 0.f, 0.f};

    for (int k0 = 0; k0 < EMB; k0 += 64) {
        #pragma unroll
        for (int j = 0; j < 4; ++j) {
            int rbase = j * 32 + wave * 8;
            int row = rbase + lr;
            int cs = cc ^ (row & 7);
            const ushort* ga = A + (size_t)(m0 + row) * EMB + k0 + cs * 8;
            const ushort* gb = Bt + (size_t)(n0 + row) * EMB + k0 + cs * 8;
            __builtin_amdgcn_global_load_lds(
                (const __attribute__((address_space(1))) void*)ga,
                (__attribute__((address_space(3))) void*)&As[rbase * 64], 16, 0, 0);
            __builtin_amdgcn_global_load_lds(
                (const __attribute__((address_space(1))) void*)gb,
                (__attribute__((address_space(3))) void*)&Bs[rbase * 64], 16, 0, 0);
        }
        __syncthreads();
        #pragma unroll
        for (int kk = 0; kk < 2; ++kk) {
            short8 a[4], b[4];
            #pragma unroll
            for (int m = 0; m < 4; ++m) {
                int row = wm * 64 + m * 16 + lrow;
                int c2 = (kk * 4 + lk) ^ (row & 7);
                a[m] = *(const short8*)&As[row * 64 + c2 * 8];
            }
            #pragma unroll
            for (int n = 0; n < 4; ++n) {
                int row = wn * 64 + n * 16 + lrow;
                int c2 = (kk * 4 + lk) ^ (row & 7);
                b[n] = *(const short8*)&Bs[row * 64 + c2 * 8];
            }
            #pragma unroll
            for (int m = 0; m < 4; ++m)
                #pragma unroll
                for (int n = 0; n < 4; ++n)
                    acc[m][n] = __builtin_amdgcn_mfma_f32_16x16x32_bf16(
                        a[m], b[n], acc[m][n], 0, 0, 0);
        }
        __syncthreads();
    }

    if (z < 2) {
        ushort* out = (z == 0) ? qb : kbf;
        #pragma unroll
        for (int n = 0; n < 4; ++n) {
            int col = n0 + wn * 64 + n * 16 + lrow;
            #pragma unroll
            for (int m = 0; m < 4; ++m) {
                int rbase = m0 + wm * 64 + m * 16 + lk * 4;
                #pragma unroll
                for (int j = 0; j < 4; ++j)
                    out[(size_t)(rbase + j) * EMB + col] = bfb(acc[m][n][j]);
            }
        }
    } else {
        // v written directly transposed: vt[b][e][t]
        #pragma unroll
        for (int n = 0; n < 4; ++n) {
            int col = n0 + wn * 64 + n * 16 + lrow;   // e
            #pragma unroll
            for (int m = 0; m < 4; ++m) {
                int rbase = m0 + wm * 64 + m * 16 + lk * 4;
                #pragma unroll
                for (int j = 0; j < 4; ++j) {
                    int row = rbase + j;              // token
                    int bb = row >> 10, rr = row & 1023;
                    vt[((size_t)bb * EMB + col) * TSEQ + rr] = bfb(acc[m][n][j]);
                }
            }
        }
    }
}

// ---------------- MFMA flash attention: 1 wave / 16 Q-rows, KB=32, dbuf K/V ----------------
__global__ __launch_bounds__(64) void k_attn(const ushort* __restrict__ qg,
                                             const ushort* __restrict__ kg,
                                             const ushort* __restrict__ vt,
                                             ushort* __restrict__ ao) {
    __shared__ ushort K_s[2][32 * 256];
    __shared__ ushort V_s[2][256 * 32];

    int strip = blockIdx.x;
    int b = strip >> 6;
    int qbase = (strip & 63) * 16;
    int lane = threadIdx.x;
    int q = lane & 15, lk = lane >> 4;

    const ushort* qrow = qg + (size_t)(b * TSEQ + qbase + q) * EMB;
    short8 qf[8];
    #pragma unroll
    for (int c = 0; c < 8; ++c)
        qf[c] = *(const short8*)&qrow[c * 32 + lk * 8];

    f32x4 o[16];
    #pragma unroll
    for (int i = 0; i < 16; ++i) o[i] = (f32x4){0.f, 0.f, 0.f, 0.f};
    float m_run = -1e30f, l_run = 0.f;

    auto STAGE = [&](int buf, int st) {
        const ushort* kbase = kg + (size_t)(b * TSEQ + st * 32) * EMB;
        #pragma unroll
        for (int t = 0; t < 16; ++t) {
            int r = t * 2 + (lane >> 5);
            int slot = lane & 31;
            int chunk = slot ^ (r & 7);
            const ushort* src = kbase + r * EMB + chunk * 8;
            __builtin_amdgcn_global_load_lds(
                (const __attribute__((address_space(1))) void*)src,
                (__attribute__((address_space(3))) void*)&K_s[buf][t * 512], 16, 0, 0);
        }
        #pragma unroll
        for (int t = 0; t < 16; ++t) {
            int e = t * 16 + (lane >> 2);
            int slot = lane & 3;
            int chunk = slot ^ (e & 3);
            const ushort* src = vt + ((size_t)b * EMB + e) * TSEQ + st * 32 + chunk * 8;
            __builtin_amdgcn_global_load_lds(
                (const __attribute__((address_space(1))) void*)src,
                (__attribute__((address_space(3))) void*)&V_s[buf][t * 512], 16, 0, 0);
        }
    };

    int st_last = (qbase + 15) >> 5;
    STAGE(0, 0);
    int buf = 0;

    for (int st = 0; st <= st_last; ++st) {
        if (st < st_last) {
            STAGE(buf ^ 1, st + 1);                       // prefetch next tile
            asm volatile("s_waitcnt vmcnt(32)" ::: "memory");  // current tile done
        } else {
            asm volatile("s_waitcnt vmcnt(0)" ::: "memory");
        }

        f32x4 sa0 = (f32x4){0.f, 0.f, 0.f, 0.f};
        f32x4 sa1 = (f32x4){0.f, 0.f, 0.f, 0.f};
        #pragma unroll
        for (int c = 0; c < 8; ++c) {
            int sl = (c * 4 + lk) ^ (q & 7);
            short8 kf0 = *(const short8*)&K_s[buf][q * 256 + sl * 8];
            short8 kf1 = *(const short8*)&K_s[buf][(16 + q) * 256 + sl * 8];
            sa0 = __builtin_amdgcn_mfma_f32_16x16x32_bf16(kf0, qf[c], sa0, 0, 0, 0);
            sa1 = __builtin_amdgcn_mfma_f32_16x16x32_bf16(kf1, qf[c], sa1, 0, 0, 0);
        }

        float sv0[4], sv1[4];
        #pragma unroll
        for (int j = 0; j < 4; ++j) { sv0[j] = sa0[j] * 0.0625f; sv1[j] = sa1[j] * 0.0625f; }
        if (st == st_last) {
            int qgl = qbase + q;
            #pragma unroll
            for (int j = 0; j < 4; ++j) {
                if (st * 32 + lk * 4 + j > qgl)      sv0[j] = -1e30f;
                if (st * 32 + 16 + lk * 4 + j > qgl) sv1[j] = -1e30f;
            }
        }

        float tm = sv0[0];
        #pragma unroll
        for (int j = 1; j < 4; ++j) tm = fmaxf(tm, sv0[j]);
        #pragma unroll
        for (int j = 0; j < 4; ++j) tm = fmaxf(tm, sv1[j]);
        tm = fmaxf(tm, __shfl_xor(tm, 16));
        tm = fmaxf(tm, __shfl_xor(tm, 32));
        float mn = fmaxf(m_run, tm);
        float alpha = __expf(m_run - mn);
        float p0[4], p1[4], ts = 0.f;
        #pragma unroll
        for (int j = 0; j < 4; ++j) {
            p0[j] = __expf(sv0[j] - mn);
            p1[j] = __expf(sv1[j] - mn);
            ts += p0[j] + p1[j];
        }
        ts += __shfl_xor(ts, 16);
        ts += __shfl_xor(ts, 32);
        l_run = l_run * alpha + ts;
        m_run = mn;

        #pragma unroll
        for (int i = 0; i < 16; ++i) {
            o[i][0] *= alpha; o[i][1] *= alpha; o[i][2] *= alpha; o[i][3] *= alpha;
        }

        unsigned c0 = pk2(p0[0], p0[1]), c1 = pk2(p0[2], p0[3]);
        unsigned d0 = pk2(p1[0], p1[1]), d1 = pk2(p1[2], p1[3]);
        int sA = q + 32 * (lk & 1);
        int sB = sA + 16;
        unsigned a0c = __shfl(c0, sA), a1c = __shfl(c1, sA);
        unsigned b0c = __shfl(c0, sB), b1c = __shfl(c1, sB);
        unsigned a0d = __shfl(d0, sA), a1d = __shfl(d1, sA);
        unsigned b0d = __shfl(d0, sB), b1d = __shfl(d1, sB);
        bool hi = (lk >> 1) != 0;
        union { short8 s; unsigned u[4]; } pb;
        pb.u[0] = hi ? a0d : a0c;
        pb.u[1] = hi ? a1d : a1c;
        pb.u[2] = hi ? b0d : b0c;
        pb.u[3] = hi ? b1d : b1c;

        #pragma unroll
        for (int eb = 0; eb < 16; ++eb) {
            int er = eb * 16 + q;
            int sl = lk ^ (er & 3);
            short8 vf = *(const short8*)&V_s[buf][er * 32 + sl * 8];
            o[eb] = __builtin_amdgcn_mfma_f32_16x16x32_bf16(vf, pb.s, o[eb], 0, 0, 0);
        }
        buf ^= 1;
    }

    float inv_l = 1.f / l_run;
    ushort* orow = ao + (size_t)(b * TSEQ + qbase + q) * EMB;
    #pragma unroll
    for (int eb = 0; eb < 16; ++eb) {
        uint2 w;
        w.x = pk2(o[eb][0] * inv_l, o[eb][1] * inv_l);
        w.y = pk2(o[eb][2] * inv_l, o[eb][3] * inv_l);
        *(uint2*)&orow[eb * 16 + lk * 4] = w;
    }
}

// ---------------- logits GEMM: no LDS, register fragments from L2 ----------------
// 6 blocks/CU (24 waves) hide L2 latency; nontemporal C stores keep A/Wt L2-resident.
__global__ __launch_bounds__(256, 6) void k_gemm(const ushort* __restrict__ A,
                                                 const ushort* __restrict__ Bt,
                                                 const float* __restrict__ lmb,
                                                 float* __restrict__ C,
                                                 float2* __restrict__ part) {
    __shared__ float fbM[128], fbS[128];

    int linear = blockIdx.x;
    int swz = (linear & 7) * 1000 + (linear >> 3);   // bijective XCD swizzle (8000%8==0)
    int m0 = (swz & 31) * 128;
    int nb = swz >> 5;
    int n0 = nb * 128;

    int tid = threadIdx.x;
    int lane = tid & 63, wave = tid >> 6;
    int wm = wave >> 1, wn = wave & 1;
    int lrow = lane & 15, lk = lane >> 4;

    const ushort* Ab = A  + (size_t)(m0 + wm * 64 + lrow) * EMB + lk * 8;
    const ushort* Bb = Bt + (size_t)(n0 + wn * 64 + lrow) * EMB + lk * 8;

    float biasv[4];
    #pragma unroll
    for (int n = 0; n < 4; ++n)
        biasv[n] = lmb[n0 + wn * 64 + n * 16 + lrow];

    f32x4 acc[4][4];
    #pragma unroll
    for (int i = 0; i < 4; ++i)
        #pragma unroll
        for (int j = 0; j < 4; ++j)
            acc[i][j] = (f32x4){0.f, 0.f, 0.f, 0.f};

    #pragma unroll
    for (int kk = 0; kk < 8; ++kk) {
        short8 a[4], b[4];
        #pragma unroll
        for (int m = 0; m < 4; ++m)
            a[m] = *(const short8*)&Ab[(size_t)m * 16 * EMB + kk * 32];
        #pragma unroll
        for (int n = 0; n < 4; ++n)
            b[n] = *(const short8*)&Bb[(size_t)n * 16 * EMB + kk * 32];
        #pragma unroll
        for (int m = 0; m < 4; ++m)
            #pragma unroll
            for (int n = 0; n < 4; ++n)
                acc[m][n] = __builtin_amdgcn_mfma_f32_16x16x32_bf16(
                    a[m], b[n], acc[m][n], 0, 0, 0);
    }

    // write logits — nontemporal (evict-first; don't thrash the A/Wt panels)
    #pragma unroll
    for (int n = 0; n < 4; ++n) {
        int col = n0 + wn * 64 + n * 16 + lrow;
        #pragma unroll
        for (int m = 0; m < 4; ++m) {
            int rbase = m0 + wm * 64 + m * 16 + lk * 4;
            #pragma unroll
            for (int j = 0; j < 4; ++j)
                __builtin_nontemporal_store(acc[m][n][j] + biasv[n],
                                            &C[(size_t)(rbase + j) * VOCAB + col]);
        }
    }

    // per-row logsumexp partial over this block's 128 cols
    float pM[4][4], pS[4][4];
    #pragma unroll
    for (int m = 0; m < 4; ++m) {
        #pragma unroll
        for (int j = 0; j < 4; ++j) {
            float v0 = acc[m][0][j] + biasv[0];
            float v1 = acc[m][1][j] + biasv[1];
            float v2 = acc[m][2][j] + biasv[2];
            float v3 = acc[m][3][j] + biasv[3];
            float tM = fmaxf(fmaxf(v0, v1), fmaxf(v2, v3));
            float tS = __expf(v0 - tM) + __expf(v1 - tM) + __expf(v2 - tM) + __expf(v3 - tM);
            #pragma unroll
            for (int off = 1; off < 16; off <<= 1) {
                float oM = __shfl_xor(tM, off);
                float oS = __shfl_xor(tS, off);
                float nM = fmaxf(tM, oM);
                tS = tS * __expf(tM - nM) + oS * __expf(oM - nM);
                tM = nM;
            }
            pM[m][j] = tM; pS[m][j] = tS;
        }
    }
    // combine the two wn halves via tiny LDS; raw barrier + lgkmcnt only
    if (wn == 0 && lrow == 0) {
        #pragma unroll
        for (int m = 0; m < 4; ++m)
            #pragma unroll
            for (int j = 0; j < 4; ++j) {
                int r64 = m * 16 + lk * 4 + j;
                fbM[wm * 64 + r64] = pM[m][j];
                fbS[wm * 64 + r64] = pS[m][j];
            }
    }
    asm volatile("s_waitcnt lgkmcnt(0)" ::: "memory");
    __builtin_amdgcn_s_barrier();
    __builtin_amdgcn_sched_barrier(0);
    if (wn == 1 && lrow == 0) {
        #pragma unroll
        for (int m = 0; m < 4; ++m)
            #pragma unroll
            for (int j = 0; j < 4; ++j) {
                int r64 = m * 16 + lk * 4 + j;
                float oM = fbM[wm * 64 + r64];
                float oS = fbS[wm * 64 + r64];
                float tM = pM[m][j], tS = pS[m][j];
                float nM = fmaxf(tM, oM);
                float nS = tS * __expf(tM - nM) + oS * __expf(oM - nM);
                part[(size_t)(m0 + wm * 64 + r64) * NBLKN + nb] = make_float2(nM, nS);
            }
    }
}

// ---------------- loss reduce over partials ----------------
__global__ __launch_bounds__(256) void k_reduce(const float2* __restrict__ part,
                                                const float* __restrict__ logits,
                                                const int* __restrict__ tgt,
                                                float* __restrict__ loss) {
    int row = blockIdx.x;
    int tid = threadIdx.x;
    float M = -1e30f, S = 0.f;
    for (int i = tid; i < NBLKN; i += 256) {
        float2 p = part[(size_t)row * NBLKN + i];
        float nM = fmaxf(M, p.x);
        S = S * __expf(M - nM) + p.y * __expf(p.x - nM);
        M = nM;
    }
    #pragma unroll
    for (int off = 1; off < 64; off <<= 1) {
        float oM = __shfl_xor(M, off);
        float oS = __shfl_xor(S, off);
        float nM = fmaxf(M, oM);
        S = S * __expf(M - nM) + oS * __expf(oM - nM);
        M = nM;
    }
    __shared__ float wm[4], ws[4];
    int lane = tid & 63, wave = tid >> 6;
    if (lane == 0) { wm[wave] = M; ws[wave] = S; }
    __syncthreads();
    if (tid == 0) {
        float fM = wm[0], fS = ws[0];
        #pragma unroll
        for (int w = 1; w < 4; ++w) {
            float nM = fmaxf(fM, wm[w]);
            fS = fS * __expf(fM - nM) + ws[w] * __expf(wm[w] - nM);
            fM = nM;
        }
        float lse = fM + __logf(fS);
        float tl = logits[(size_t)row * VOCAB + tgt[row]];
        atomicAdd(loss, (lse - tl) * (1.0f / 4096.0f));
    }
}

extern "C" void kernel_launch(void* const* d_in, const int* in_sizes, int n_in,
                              void* d_out, int out_size, void* d_ws, size_t ws_size,
                              hipStream_t stream) {
    (void)in_sizes; (void)n_in; (void)ws_size;
    const int*   idx     = (const int*)d_in[0];
    const int*   targets = (const int*)d_in[1];
    const float* tok     = (const float*)d_in[2];
    const float* pos     = (const float*)d_in[3];
    const float* Wk      = (const float*)d_in[4];
    const float* Wq      = (const float*)d_in[5];
    const float* Wv      = (const float*)d_in[6];
    const float* lmW     = (const float*)d_in[7];
    const float* lmb     = (const float*)d_in[8];

    float* logits = (float*)d_out;
    float* loss   = logits + (size_t)out_size - 1;

    const size_t MB = 1u << 20;
    char* w = (char*)d_ws;
    ushort* Wt3  = (ushort*)(w);                 // 384 KB
    ushort* xb   = (ushort*)(w + MB / 2);        // 2 MB
    ushort* qb   = (ushort*)(w + 5 * MB / 2);    // 2 MB
    ushort* kbf  = (ushort*)(w + 9 * MB / 2);    // 2 MB
    ushort* vt   = (ushort*)(w + 13 * MB / 2);   // 2 MB
    ushort* ao   = (ushort*)(w + 17 * MB / 2);   // 2 MB
    ushort* Wt   = (ushort*)(w + 21 * MB / 2);   // 16 MB
    float2* part = (float2*)(w + 28 * MB);       // 8 MB

    hipMemsetAsync(loss, 0, sizeof(float), stream);
    k_conv<<<dim3(1024, 8), 256, 0, stream>>>(lmW, Wq, Wk, Wv, Wt, Wt3);
    k_embed<<<NROWS, 256, 0, stream>>>(idx, tok, pos, xb);
    k_qkv_mm<<<dim3(NROWS / 128, EMB / 128, 3), 256, 0, stream>>>(xb, Wt3, qb, kbf, vt);
    k_attn<<<256, 64, 0, stream>>>(qb, kbf, vt, ao);
    k_gemm<<<8000, 256, 0, stream>>>(ao, Wt, lmb, logits, part);
    k_reduce<<<NROWS, 256, 0, stream>>>(part, logits, targets, loss);
}

// Round 8
// 396.963 us; speedup vs baseline: 2.6461x; 2.6461x over previous
//
#include <hip/hip_runtime.h>
#include <hip/hip_bf16.h>
#include <math.h>

#define VOCAB 32000
#define EMB   256
#define TSEQ  1024
#define NROWS 4096
#define NBLKN 250   // VOCAB/128

typedef __attribute__((ext_vector_type(8))) short short8;
typedef __attribute__((ext_vector_type(4))) float f32x4;

static __device__ __forceinline__ unsigned short bfb(float x) {
    __hip_bfloat16 h = __float2bfloat16(x);
    return *(unsigned short*)&h;
}
static __device__ __forceinline__ unsigned pk2(float a, float b) {
    return (unsigned)bfb(a) | ((unsigned)bfb(b) << 16);
}

// ---------------- embed: xb = bf16(tok_table[idx] + pos_table[t]) ----------------
__global__ __launch_bounds__(256) void k_embed(const int* __restrict__ idx,
                                               const float* __restrict__ tok,
                                               const float* __restrict__ pos,
                                               ushort* __restrict__ xb) {
    int row = blockIdx.x;
    int t = row & (TSEQ - 1);
    int token = idx[row];
    int e = threadIdx.x;
    xb[row * EMB + e] = bfb(tok[token * EMB + e] + pos[t * EMB + e]);
}

// ---------------- transpose+convert: lm_W (x<1000) and Wq/Wk/Wv (x>=1000) ----------------
__global__ __launch_bounds__(256) void k_conv(const float* __restrict__ lmW,
                                              const float* __restrict__ Wq,
                                              const float* __restrict__ Wk,
                                              const float* __restrict__ Wv,
                                              ushort* __restrict__ Wt,
                                              ushort* __restrict__ Wt3) {
    __shared__ float T[32][33];
    int bx = blockIdx.x, by = blockIdx.y;
    const float* W; ushort* out; int n0, k0, ncols;
    if (bx < 1000) {
        W = lmW; out = Wt; n0 = bx * 32; k0 = by * 32; ncols = VOCAB;
    } else {
        int xi = bx - 1000;          // 0..23
        int z = xi >> 3;
        W = (z == 0) ? Wq : (z == 1) ? Wk : Wv;
        out = Wt3 + (size_t)z * EMB * EMB;
        n0 = (xi & 7) * 32; k0 = by * 32; ncols = EMB;
    }
    int tx = threadIdx.x & 31, ty = threadIdx.x >> 5;
    #pragma unroll
    for (int i = 0; i < 4; ++i) {
        int kk = ty + 8 * i;
        T[kk][tx] = W[(size_t)(k0 + kk) * ncols + n0 + tx];
    }
    __syncthreads();
    #pragma unroll
    for (int i = 0; i < 4; ++i) {
        int r = ty + 8 * i;
        out[(size_t)(n0 + r) * EMB + k0 + tx] = bfb(T[tx][r]);
    }
}

// ---------------- qkv MFMA GEMM: q/k row-major bf16; v written transposed (vt) ----------------
__global__ __launch_bounds__(256) void k_qkv_mm(const ushort* __restrict__ A,
                                                const ushort* __restrict__ Wt3,
                                                ushort* __restrict__ qb,
                                                ushort* __restrict__ kbf,
                                                ushort* __restrict__ vt) {
    __shared__ ushort As[128 * 64];
    __shared__ ushort Bs[128 * 64];

    int z = blockIdx.z;
    const ushort* Bt = Wt3 + (size_t)z * EMB * EMB;

    int m0 = blockIdx.x * 128, n0 = blockIdx.y * 128;
    int tid = threadIdx.x;
    int lane = tid & 63, wave = tid >> 6;
    int wm = wave >> 1, wn = wave & 1;
    int lr = lane >> 3, cc = lane & 7;
    int lrow = lane & 15, lk = lane >> 4;

    f32x4 acc[4][4];
    #pragma unroll
    for (int i = 0; i < 4; ++i)
        #pragma unroll
        for (int j = 0; j < 4; ++j)
            acc[i][j] = (f32x4){0.f, 0.f, 0.f, 0.f};

    for (int k0 = 0; k0 < EMB; k0 += 64) {
        #pragma unroll
        for (int j = 0; j < 4; ++j) {
            int rbase = j * 32 + wave * 8;
            int row = rbase + lr;
            int cs = cc ^ (row & 7);
            const ushort* ga = A + (size_t)(m0 + row) * EMB + k0 + cs * 8;
            const ushort* gb = Bt + (size_t)(n0 + row) * EMB + k0 + cs * 8;
            __builtin_amdgcn_global_load_lds(
                (const __attribute__((address_space(1))) void*)ga,
                (__attribute__((address_space(3))) void*)&As[rbase * 64], 16, 0, 0);
            __builtin_amdgcn_global_load_lds(
                (const __attribute__((address_space(1))) void*)gb,
                (__attribute__((address_space(3))) void*)&Bs[rbase * 64], 16, 0, 0);
        }
        __syncthreads();
        #pragma unroll
        for (int kk = 0; kk < 2; ++kk) {
            short8 a[4], b[4];
            #pragma unroll
            for (int m = 0; m < 4; ++m) {
                int row = wm * 64 + m * 16 + lrow;
                int c2 = (kk * 4 + lk) ^ (row & 7);
                a[m] = *(const short8*)&As[row * 64 + c2 * 8];
            }
            #pragma unroll
            for (int n = 0; n < 4; ++n) {
                int row = wn * 64 + n * 16 + lrow;
                int c2 = (kk * 4 + lk) ^ (row & 7);
                b[n] = *(const short8*)&Bs[row * 64 + c2 * 8];
            }
            #pragma unroll
            for (int m = 0; m < 4; ++m)
                #pragma unroll
                for (int n = 0; n < 4; ++n)
                    acc[m][n] = __builtin_amdgcn_mfma_f32_16x16x32_bf16(
                        a[m], b[n], acc[m][n], 0, 0, 0);
        }
        __syncthreads();
    }

    if (z < 2) {
        ushort* out = (z == 0) ? qb : kbf;
        #pragma unroll
        for (int n = 0; n < 4; ++n) {
            int col = n0 + wn * 64 + n * 16 + lrow;
            #pragma unroll
            for (int m = 0; m < 4; ++m) {
                int rbase = m0 + wm * 64 + m * 16 + lk * 4;
                #pragma unroll
                for (int j = 0; j < 4; ++j)
                    out[(size_t)(rbase + j) * EMB + col] = bfb(acc[m][n][j]);
            }
        }
    } else {
        // v written directly transposed: vt[b][e][t]
        #pragma unroll
        for (int n = 0; n < 4; ++n) {
            int col = n0 + wn * 64 + n * 16 + lrow;   // e
            #pragma unroll
            for (int m = 0; m < 4; ++m) {
                int rbase = m0 + wm * 64 + m * 16 + lk * 4;
                #pragma unroll
                for (int j = 0; j < 4; ++j) {
                    int row = rbase + j;              // token
                    int bb = row >> 10, rr = row & 1023;
                    vt[((size_t)bb * EMB + col) * TSEQ + rr] = bfb(acc[m][n][j]);
                }
            }
        }
    }
}

// ---------------- MFMA flash attention: 1 wave / 16 Q-rows, KB=32, dbuf K/V ----------------
__global__ __launch_bounds__(64) void k_attn(const ushort* __restrict__ qg,
                                             const ushort* __restrict__ kg,
                                             const ushort* __restrict__ vt,
                                             ushort* __restrict__ ao) {
    __shared__ ushort K_s[2][32 * 256];
    __shared__ ushort V_s[2][256 * 32];

    int strip = blockIdx.x;
    int b = strip >> 6;
    int qbase = (strip & 63) * 16;
    int lane = threadIdx.x;
    int q = lane & 15, lk = lane >> 4;

    const ushort* qrow = qg + (size_t)(b * TSEQ + qbase + q) * EMB;
    short8 qf[8];
    #pragma unroll
    for (int c = 0; c < 8; ++c)
        qf[c] = *(const short8*)&qrow[c * 32 + lk * 8];

    f32x4 o[16];
    #pragma unroll
    for (int i = 0; i < 16; ++i) o[i] = (f32x4){0.f, 0.f, 0.f, 0.f};
    float m_run = -1e30f, l_run = 0.f;

    auto STAGE = [&](int buf, int st) {
        const ushort* kbase = kg + (size_t)(b * TSEQ + st * 32) * EMB;
        #pragma unroll
        for (int t = 0; t < 16; ++t) {
            int r = t * 2 + (lane >> 5);
            int slot = lane & 31;
            int chunk = slot ^ (r & 7);
            const ushort* src = kbase + r * EMB + chunk * 8;
            __builtin_amdgcn_global_load_lds(
                (const __attribute__((address_space(1))) void*)src,
                (__attribute__((address_space(3))) void*)&K_s[buf][t * 512], 16, 0, 0);
        }
        #pragma unroll
        for (int t = 0; t < 16; ++t) {
            int e = t * 16 + (lane >> 2);
            int slot = lane & 3;
            int chunk = slot ^ (e & 3);
            const ushort* src = vt + ((size_t)b * EMB + e) * TSEQ + st * 32 + chunk * 8;
            __builtin_amdgcn_global_load_lds(
                (const __attribute__((address_space(1))) void*)src,
                (__attribute__((address_space(3))) void*)&V_s[buf][t * 512], 16, 0, 0);
        }
    };

    int st_last = (qbase + 15) >> 5;
    STAGE(0, 0);
    int buf = 0;

    for (int st = 0; st <= st_last; ++st) {
        if (st < st_last) {
            STAGE(buf ^ 1, st + 1);                       // prefetch next tile
            asm volatile("s_waitcnt vmcnt(32)" ::: "memory");  // current tile done
        } else {
            asm volatile("s_waitcnt vmcnt(0)" ::: "memory");
        }

        f32x4 sa0 = (f32x4){0.f, 0.f, 0.f, 0.f};
        f32x4 sa1 = (f32x4){0.f, 0.f, 0.f, 0.f};
        #pragma unroll
        for (int c = 0; c < 8; ++c) {
            int sl = (c * 4 + lk) ^ (q & 7);
            short8 kf0 = *(const short8*)&K_s[buf][q * 256 + sl * 8];
            short8 kf1 = *(const short8*)&K_s[buf][(16 + q) * 256 + sl * 8];
            sa0 = __builtin_amdgcn_mfma_f32_16x16x32_bf16(kf0, qf[c], sa0, 0, 0, 0);
            sa1 = __builtin_amdgcn_mfma_f32_16x16x32_bf16(kf1, qf[c], sa1, 0, 0, 0);
        }

        float sv0[4], sv1[4];
        #pragma unroll
        for (int j = 0; j < 4; ++j) { sv0[j] = sa0[j] * 0.0625f; sv1[j] = sa1[j] * 0.0625f; }
        if (st == st_last) {
            int qgl = qbase + q;
            #pragma unroll
            for (int j = 0; j < 4; ++j) {
                if (st * 32 + lk * 4 + j > qgl)      sv0[j] = -1e30f;
                if (st * 32 + 16 + lk * 4 + j > qgl) sv1[j] = -1e30f;
            }
        }

        float tm = sv0[0];
        #pragma unroll
        for (int j = 1; j < 4; ++j) tm = fmaxf(tm, sv0[j]);
        #pragma unroll
        for (int j = 0; j < 4; ++j) tm = fmaxf(tm, sv1[j]);
        tm = fmaxf(tm, __shfl_xor(tm, 16));
        tm = fmaxf(tm, __shfl_xor(tm, 32));
        float mn = fmaxf(m_run, tm);
        float alpha = __expf(m_run - mn);
        float p0[4], p1[4], ts = 0.f;
        #pragma unroll
        for (int j = 0; j < 4; ++j) {
            p0[j] = __expf(sv0[j] - mn);
            p1[j] = __expf(sv1[j] - mn);
            ts += p0[j] + p1[j];
        }
        ts += __shfl_xor(ts, 16);
        ts += __shfl_xor(ts, 32);
        l_run = l_run * alpha + ts;
        m_run = mn;

        #pragma unroll
        for (int i = 0; i < 16; ++i) {
            o[i][0] *= alpha; o[i][1] *= alpha; o[i][2] *= alpha; o[i][3] *= alpha;
        }

        unsigned c0 = pk2(p0[0], p0[1]), c1 = pk2(p0[2], p0[3]);
        unsigned d0 = pk2(p1[0], p1[1]), d1 = pk2(p1[2], p1[3]);
        int sA = q + 32 * (lk & 1);
        int sB = sA + 16;
        unsigned a0c = __shfl(c0, sA), a1c = __shfl(c1, sA);
        unsigned b0c = __shfl(c0, sB), b1c = __shfl(c1, sB);
        unsigned a0d = __shfl(d0, sA), a1d = __shfl(d1, sA);
        unsigned b0d = __shfl(d0, sB), b1d = __shfl(d1, sB);
        bool hi = (lk >> 1) != 0;
        union { short8 s; unsigned u[4]; } pb;
        pb.u[0] = hi ? a0d : a0c;
        pb.u[1] = hi ? a1d : a1c;
        pb.u[2] = hi ? b0d : b0c;
        pb.u[3] = hi ? b1d : b1c;

        #pragma unroll
        for (int eb = 0; eb < 16; ++eb) {
            int er = eb * 16 + q;
            int sl = lk ^ (er & 3);
            short8 vf = *(const short8*)&V_s[buf][er * 32 + sl * 8];
            o[eb] = __builtin_amdgcn_mfma_f32_16x16x32_bf16(vf, pb.s, o[eb], 0, 0, 0);
        }
        buf ^= 1;
    }

    float inv_l = 1.f / l_run;
    ushort* orow = ao + (size_t)(b * TSEQ + qbase + q) * EMB;
    #pragma unroll
    for (int eb = 0; eb < 16; ++eb) {
        uint2 w;
        w.x = pk2(o[eb][0] * inv_l, o[eb][1] * inv_l);
        w.y = pk2(o[eb][2] * inv_l, o[eb][3] * inv_l);
        *(uint2*)&orow[eb * 16 + lk * 4] = w;
    }
}

// ---------------- logits GEMM: BK=32 double-buffer, counted vmcnt (T3+T4) ----------------
// 32 KB LDS + unconstrained VGPR -> 3-4 blocks/CU. Per K-step:
// {STAGE(t+1) -> vmcnt(4) -> barrier -> 16 MFMA -> barrier}; prefetch never drained to 0.
__global__ __launch_bounds__(256) void k_gemm(const ushort* __restrict__ A,
                                              const ushort* __restrict__ Bt,
                                              const float* __restrict__ lmb,
                                              float* __restrict__ C,
                                              float2* __restrict__ part) {
    __shared__ ushort As[2][128 * 32];   // 16 KB
    __shared__ ushort Bs[2][128 * 32];   // 16 KB
    __shared__ float fbM[128], fbS[128];

    int linear = blockIdx.x;
    int swz = (linear & 7) * 1000 + (linear >> 3);   // bijective XCD swizzle (8000%8==0)
    int m0 = (swz & 31) * 128;
    int nb = swz >> 5;
    int n0 = nb * 128;

    int tid = threadIdx.x;
    int lane = tid & 63, wave = tid >> 6;
    int wm = wave >> 1, wn = wave & 1;
    int lrow = lane & 15, lk = lane >> 4;

    auto STAGE = [&](int bufi, int t) {
        int k0 = t * 32;
        #pragma unroll
        for (int i = 0; i < 2; ++i) {
            int rbase = i * 64 + wave * 16;
            int row = rbase + (lane >> 2);
            int cs = (lane & 3) ^ (row & 3);
            const ushort* ga = A + (size_t)(m0 + row) * EMB + k0 + cs * 8;
            const ushort* gb = Bt + (size_t)(n0 + row) * EMB + k0 + cs * 8;
            __builtin_amdgcn_global_load_lds(
                (const __attribute__((address_space(1))) void*)ga,
                (__attribute__((address_space(3))) void*)&As[bufi][rbase * 32], 16, 0, 0);
            __builtin_amdgcn_global_load_lds(
                (const __attribute__((address_space(1))) void*)gb,
                (__attribute__((address_space(3))) void*)&Bs[bufi][rbase * 32], 16, 0, 0);
        }
    };

    float biasv[4];
    #pragma unroll
    for (int n = 0; n < 4; ++n)
        biasv[n] = lmb[n0 + wn * 64 + n * 16 + lrow];

    f32x4 acc[4][4];
    #pragma unroll
    for (int i = 0; i < 4; ++i)
        #pragma unroll
        for (int j = 0; j < 4; ++j)
            acc[i][j] = (f32x4){0.f, 0.f, 0.f, 0.f};

    STAGE(0, 0);   // 4 loads in flight

    #pragma unroll
    for (int t = 0; t < 8; ++t) {
        if (t < 7) {
            STAGE((t + 1) & 1, t + 1);                       // +4 -> 8 in flight
            asm volatile("s_waitcnt vmcnt(4)" ::: "memory"); // tile t landed
        } else {
            asm volatile("s_waitcnt vmcnt(0)" ::: "memory");
        }
        __builtin_amdgcn_sched_barrier(0);
        __builtin_amdgcn_s_barrier();                        // tile t visible to all

        const ushort* Ab = As[t & 1];
        const ushort* Bb = Bs[t & 1];
        short8 a[4], b[4];
        #pragma unroll
        for (int m = 0; m < 4; ++m) {
            int row = wm * 64 + m * 16 + lrow;
            int sl = lk ^ (row & 3);
            a[m] = *(const short8*)&Ab[row * 32 + sl * 8];
        }
        #pragma unroll
        for (int n = 0; n < 4; ++n) {
            int row = wn * 64 + n * 16 + lrow;
            int sl = lk ^ (row & 3);
            b[n] = *(const short8*)&Bb[row * 32 + sl * 8];
        }
        #pragma unroll
        for (int m = 0; m < 4; ++m)
            #pragma unroll
            for (int n = 0; n < 4; ++n)
                acc[m][n] = __builtin_amdgcn_mfma_f32_16x16x32_bf16(
                    a[m], b[n], acc[m][n], 0, 0, 0);

        asm volatile("s_waitcnt lgkmcnt(0)" ::: "memory");   // ds_reads of buf done
        __builtin_amdgcn_sched_barrier(0);
        __builtin_amdgcn_s_barrier();                        // buf safe to overwrite next iter
    }

    // write logits
    #pragma unroll
    for (int n = 0; n < 4; ++n) {
        int col = n0 + wn * 64 + n * 16 + lrow;
        #pragma unroll
        for (int m = 0; m < 4; ++m) {
            int rbase = m0 + wm * 64 + m * 16 + lk * 4;
            #pragma unroll
            for (int j = 0; j < 4; ++j)
                C[(size_t)(rbase + j) * VOCAB + col] = acc[m][n][j] + biasv[n];
        }
    }

    // per-row logsumexp partial over this block's 128 cols
    float pM[4][4], pS[4][4];
    #pragma unroll
    for (int m = 0; m < 4; ++m) {
        #pragma unroll
        for (int j = 0; j < 4; ++j) {
            float v0 = acc[m][0][j] + biasv[0];
            float v1 = acc[m][1][j] + biasv[1];
            float v2 = acc[m][2][j] + biasv[2];
            float v3 = acc[m][3][j] + biasv[3];
            float tM = fmaxf(fmaxf(v0, v1), fmaxf(v2, v3));
            float tS = __expf(v0 - tM) + __expf(v1 - tM) + __expf(v2 - tM) + __expf(v3 - tM);
            #pragma unroll
            for (int off = 1; off < 16; off <<= 1) {
                float oM = __shfl_xor(tM, off);
                float oS = __shfl_xor(tS, off);
                float nM = fmaxf(tM, oM);
                tS = tS * __expf(tM - nM) + oS * __expf(oM - nM);
                tM = nM;
            }
            pM[m][j] = tM; pS[m][j] = tS;
        }
    }
    // combine the two wn halves via tiny LDS; raw barrier + lgkmcnt only
    // (C-stores stay in flight — no vmcnt drain here)
    if (wn == 0 && lrow == 0) {
        #pragma unroll
        for (int m = 0; m < 4; ++m)
            #pragma unroll
            for (int j = 0; j < 4; ++j) {
                int r64 = m * 16 + lk * 4 + j;
                fbM[wm * 64 + r64] = pM[m][j];
                fbS[wm * 64 + r64] = pS[m][j];
            }
    }
    asm volatile("s_waitcnt lgkmcnt(0)" ::: "memory");
    __builtin_amdgcn_s_barrier();
    __builtin_amdgcn_sched_barrier(0);
    if (wn == 1 && lrow == 0) {
        #pragma unroll
        for (int m = 0; m < 4; ++m)
            #pragma unroll
            for (int j = 0; j < 4; ++j) {
                int r64 = m * 16 + lk * 4 + j;
                float oM = fbM[wm * 64 + r64];
                float oS = fbS[wm * 64 + r64];
                float tM = pM[m][j], tS = pS[m][j];
                float nM = fmaxf(tM, oM);
                float nS = tS * __expf(tM - nM) + oS * __expf(oM - nM);
                part[(size_t)(m0 + wm * 64 + r64) * NBLKN + nb] = make_float2(nM, nS);
            }
    }
}

// ---------------- loss reduce over partials ----------------
__global__ __launch_bounds__(256) void k_reduce(const float2* __restrict__ part,
                                                const float* __restrict__ logits,
                                                const int* __restrict__ tgt,
                                                float* __restrict__ loss) {
    int row = blockIdx.x;
    int tid = threadIdx.x;
    float M = -1e30f, S = 0.f;
    for (int i = tid; i < NBLKN; i += 256) {
        float2 p = part[(size_t)row * NBLKN + i];
        float nM = fmaxf(M, p.x);
        S = S * __expf(M - nM) + p.y * __expf(p.x - nM);
        M = nM;
    }
    #pragma unroll
    for (int off = 1; off < 64; off <<= 1) {
        float oM = __shfl_xor(M, off);
        float oS = __shfl_xor(S, off);
        float nM = fmaxf(M, oM);
        S = S * __expf(M - nM) + oS * __expf(oM - nM);
        M = nM;
    }
    __shared__ float wm[4], ws[4];
    int lane = tid & 63, wave = tid >> 6;
    if (lane == 0) { wm[wave] = M; ws[wave] = S; }
    __syncthreads();
    if (tid == 0) {
        float fM = wm[0], fS = ws[0];
        #pragma unroll
        for (int w = 1; w < 4; ++w) {
            float nM = fmaxf(fM, wm[w]);
            fS = fS * __expf(fM - nM) + ws[w] * __expf(wm[w] - nM);
            fM = nM;
        }
        float lse = fM + __logf(fS);
        float tl = logits[(size_t)row * VOCAB + tgt[row]];
        atomicAdd(loss, (lse - tl) * (1.0f / 4096.0f));
    }
}

extern "C" void kernel_launch(void* const* d_in, const int* in_sizes, int n_in,
                              void* d_out, int out_size, void* d_ws, size_t ws_size,
                              hipStream_t stream) {
    (void)in_sizes; (void)n_in; (void)ws_size;
    const int*   idx     = (const int*)d_in[0];
    const int*   targets = (const int*)d_in[1];
    const float* tok     = (const float*)d_in[2];
    const float* pos     = (const float*)d_in[3];
    const float* Wk      = (const float*)d_in[4];
    const float* Wq      = (const float*)d_in[5];
    const float* Wv      = (const float*)d_in[6];
    const float* lmW     = (const float*)d_in[7];
    const float* lmb     = (const float*)d_in[8];

    float* logits = (float*)d_out;
    float* loss   = logits + (size_t)out_size - 1;

    const size_t MB = 1u << 20;
    char* w = (char*)d_ws;
    ushort* Wt3  = (ushort*)(w);                 // 384 KB
    ushort* xb   = (ushort*)(w + MB / 2);        // 2 MB
    ushort* qb   = (ushort*)(w + 5 * MB / 2);    // 2 MB
    ushort* kbf  = (ushort*)(w + 9 * MB / 2);    // 2 MB
    ushort* vt   = (ushort*)(w + 13 * MB / 2);   // 2 MB
    ushort* ao   = (ushort*)(w + 17 * MB / 2);   // 2 MB
    ushort* Wt   = (ushort*)(w + 21 * MB / 2);   // 16 MB
    float2* part = (float2*)(w + 28 * MB);       // 8 MB

    hipMemsetAsync(loss, 0, sizeof(float), stream);
    k_conv<<<dim3(1024, 8), 256, 0, stream>>>(lmW, Wq, Wk, Wv, Wt, Wt3);
    k_embed<<<NROWS, 256, 0, stream>>>(idx, tok, pos, xb);
    k_qkv_mm<<<dim3(NROWS / 128, EMB / 128, 3), 256, 0, stream>>>(xb, Wt3, qb, kbf, vt);
    k_attn<<<256, 64, 0, stream>>>(qb, kbf, vt, ao);
    k_gemm<<<8000, 256, 0, stream>>>(ao, Wt, lmb, logits, part);
    k_reduce<<<NROWS, 256, 0, stream>>>(part, logits, targets, loss);
}

// Round 9
// 322.927 us; speedup vs baseline: 3.2528x; 1.2293x over previous
//
#include <hip/hip_runtime.h>
#include <hip/hip_bf16.h>
#include <math.h>

#define VOCAB 32000
#define EMB   256
#define TSEQ  1024
#define NROWS 4096
#define NBLKN 250   // VOCAB/128

typedef __attribute__((ext_vector_type(8))) short short8;
typedef __attribute__((ext_vector_type(4))) float f32x4;

static __device__ __forceinline__ unsigned short bfb(float x) {
    __hip_bfloat16 h = __float2bfloat16(x);
    return *(unsigned short*)&h;
}
static __device__ __forceinline__ unsigned pk2(float a, float b) {
    return (unsigned)bfb(a) | ((unsigned)bfb(b) << 16);
}

// ---------------- embed: xb = bf16(tok_table[idx] + pos_table[t]) ----------------
__global__ __launch_bounds__(256) void k_embed(const int* __restrict__ idx,
                                               const float* __restrict__ tok,
                                               const float* __restrict__ pos,
                                               ushort* __restrict__ xb) {
    int row = blockIdx.x;
    int t = row & (TSEQ - 1);
    int token = idx[row];
    int e = threadIdx.x;
    xb[row * EMB + e] = bfb(tok[token * EMB + e] + pos[t * EMB + e]);
}

// ---------------- transpose+convert: lm_W (x<1000) and Wq/Wk/Wv (x>=1000) ----------------
__global__ __launch_bounds__(256) void k_conv(const float* __restrict__ lmW,
                                              const float* __restrict__ Wq,
                                              const float* __restrict__ Wk,
                                              const float* __restrict__ Wv,
                                              ushort* __restrict__ Wt,
                                              ushort* __restrict__ Wt3) {
    __shared__ float T[32][33];
    int bx = blockIdx.x, by = blockIdx.y;
    const float* W; ushort* out; int n0, k0, ncols;
    if (bx < 1000) {
        W = lmW; out = Wt; n0 = bx * 32; k0 = by * 32; ncols = VOCAB;
    } else {
        int xi = bx - 1000;          // 0..23
        int z = xi >> 3;
        W = (z == 0) ? Wq : (z == 1) ? Wk : Wv;
        out = Wt3 + (size_t)z * EMB * EMB;
        n0 = (xi & 7) * 32; k0 = by * 32; ncols = EMB;
    }
    int tx = threadIdx.x & 31, ty = threadIdx.x >> 5;
    #pragma unroll
    for (int i = 0; i < 4; ++i) {
        int kk = ty + 8 * i;
        T[kk][tx] = W[(size_t)(k0 + kk) * ncols + n0 + tx];
    }
    __syncthreads();
    #pragma unroll
    for (int i = 0; i < 4; ++i) {
        int r = ty + 8 * i;
        out[(size_t)(n0 + r) * EMB + k0 + tx] = bfb(T[tx][r]);
    }
}

// ---------------- qkv MFMA GEMM ----------------
// z<2 (q/k): swapped mfma(b,a) -> lane holds 4 consecutive cols of one token -> uint2 stores.
// z==2 (v): normal mfma(a,b) -> lane holds 4 consecutive tokens of one col -> uint2 stores into vt[b][e][t].
__global__ __launch_bounds__(256) void k_qkv_mm(const ushort* __restrict__ A,
                                                const ushort* __restrict__ Wt3,
                                                ushort* __restrict__ qb,
                                                ushort* __restrict__ kbf,
                                                ushort* __restrict__ vt) {
    __shared__ ushort As[128 * 64];
    __shared__ ushort Bs[128 * 64];

    int z = blockIdx.z;
    const ushort* Bt = Wt3 + (size_t)z * EMB * EMB;

    int m0 = blockIdx.x * 128, n0 = blockIdx.y * 128;
    int tid = threadIdx.x;
    int lane = tid & 63, wave = tid >> 6;
    int wm = wave >> 1, wn = wave & 1;
    int lr = lane >> 3, cc = lane & 7;
    int lrow = lane & 15, lk = lane >> 4;

    f32x4 acc[4][4];
    #pragma unroll
    for (int i = 0; i < 4; ++i)
        #pragma unroll
        for (int j = 0; j < 4; ++j)
            acc[i][j] = (f32x4){0.f, 0.f, 0.f, 0.f};

    for (int k0 = 0; k0 < EMB; k0 += 64) {
        #pragma unroll
        for (int j = 0; j < 4; ++j) {
            int rbase = j * 32 + wave * 8;
            int row = rbase + lr;
            int cs = cc ^ (row & 7);
            const ushort* ga = A + (size_t)(m0 + row) * EMB + k0 + cs * 8;
            const ushort* gb = Bt + (size_t)(n0 + row) * EMB + k0 + cs * 8;
            __builtin_amdgcn_global_load_lds(
                (const __attribute__((address_space(1))) void*)ga,
                (__attribute__((address_space(3))) void*)&As[rbase * 64], 16, 0, 0);
            __builtin_amdgcn_global_load_lds(
                (const __attribute__((address_space(1))) void*)gb,
                (__attribute__((address_space(3))) void*)&Bs[rbase * 64], 16, 0, 0);
        }
        __syncthreads();
        #pragma unroll
        for (int kk = 0; kk < 2; ++kk) {
            short8 a[4], b[4];
            #pragma unroll
            for (int m = 0; m < 4; ++m) {
                int row = wm * 64 + m * 16 + lrow;
                int c2 = (kk * 4 + lk) ^ (row & 7);
                a[m] = *(const short8*)&As[row * 64 + c2 * 8];
            }
            #pragma unroll
            for (int n = 0; n < 4; ++n) {
                int row = wn * 64 + n * 16 + lrow;
                int c2 = (kk * 4 + lk) ^ (row & 7);
                b[n] = *(const short8*)&Bs[row * 64 + c2 * 8];
            }
            if (z < 2) {
                #pragma unroll
                for (int m = 0; m < 4; ++m)
                    #pragma unroll
                    for (int n = 0; n < 4; ++n)
                        acc[m][n] = __builtin_amdgcn_mfma_f32_16x16x32_bf16(
                            b[n], a[m], acc[m][n], 0, 0, 0);   // swapped
            } else {
                #pragma unroll
                for (int m = 0; m < 4; ++m)
                    #pragma unroll
                    for (int n = 0; n < 4; ++n)
                        acc[m][n] = __builtin_amdgcn_mfma_f32_16x16x32_bf16(
                            a[m], b[n], acc[m][n], 0, 0, 0);
            }
        }
        __syncthreads();
    }

    if (z < 2) {
        // lane: token = lrow, col-quad = lk*4 + j (consecutive cols)
        ushort* out = (z == 0) ? qb : kbf;
        #pragma unroll
        for (int m = 0; m < 4; ++m) {
            int token = m0 + wm * 64 + m * 16 + lrow;
            #pragma unroll
            for (int n = 0; n < 4; ++n) {
                uint2 w;
                w.x = pk2(acc[m][n][0], acc[m][n][1]);
                w.y = pk2(acc[m][n][2], acc[m][n][3]);
                *(uint2*)&out[(size_t)token * EMB + n0 + wn * 64 + n * 16 + lk * 4] = w;
            }
        }
    } else {
        // lane: col e = lrow-based, tokens = lk*4 + j (consecutive) -> pack along t
        #pragma unroll
        for (int n = 0; n < 4; ++n) {
            int e = n0 + wn * 64 + n * 16 + lrow;
            #pragma unroll
            for (int m = 0; m < 4; ++m) {
                int row = m0 + wm * 64 + m * 16 + lk * 4;
                int bb = row >> 10, rr = row & 1023;
                uint2 w;
                w.x = pk2(acc[m][n][0], acc[m][n][1]);
                w.y = pk2(acc[m][n][2], acc[m][n][3]);
                *(uint2*)&vt[((size_t)bb * EMB + e) * TSEQ + rr] = w;
            }
        }
    }
}

// ---------------- MFMA flash attention: 1 wave / 16 Q-rows, KB=32, dbuf K/V ----------------
__global__ __launch_bounds__(64) void k_attn(const ushort* __restrict__ qg,
                                             const ushort* __restrict__ kg,
                                             const ushort* __restrict__ vt,
                                             ushort* __restrict__ ao) {
    __shared__ ushort K_s[2][32 * 256];
    __shared__ ushort V_s[2][256 * 32];

    int strip = blockIdx.x;
    int b = strip >> 6;
    int qbase = (strip & 63) * 16;
    int lane = threadIdx.x;
    int q = lane & 15, lk = lane >> 4;

    const ushort* qrow = qg + (size_t)(b * TSEQ + qbase + q) * EMB;
    short8 qf[8];
    #pragma unroll
    for (int c = 0; c < 8; ++c)
        qf[c] = *(const short8*)&qrow[c * 32 + lk * 8];

    f32x4 o[16];
    #pragma unroll
    for (int i = 0; i < 16; ++i) o[i] = (f32x4){0.f, 0.f, 0.f, 0.f};
    float m_run = -1e30f, l_run = 0.f;

    auto STAGE = [&](int buf, int st) {
        const ushort* kbase = kg + (size_t)(b * TSEQ + st * 32) * EMB;
        #pragma unroll
        for (int t = 0; t < 16; ++t) {
            int r = t * 2 + (lane >> 5);
            int slot = lane & 31;
            int chunk = slot ^ (r & 7);
            const ushort* src = kbase + r * EMB + chunk * 8;
            __builtin_amdgcn_global_load_lds(
                (const __attribute__((address_space(1))) void*)src,
                (__attribute__((address_space(3))) void*)&K_s[buf][t * 512], 16, 0, 0);
        }
        #pragma unroll
        for (int t = 0; t < 16; ++t) {
            int e = t * 16 + (lane >> 2);
            int slot = lane & 3;
            int chunk = slot ^ (e & 3);
            const ushort* src = vt + ((size_t)b * EMB + e) * TSEQ + st * 32 + chunk * 8;
            __builtin_amdgcn_global_load_lds(
                (const __attribute__((address_space(1))) void*)src,
                (__attribute__((address_space(3))) void*)&V_s[buf][t * 512], 16, 0, 0);
        }
    };

    int st_last = (qbase + 15) >> 5;
    STAGE(0, 0);
    int buf = 0;

    for (int st = 0; st <= st_last; ++st) {
        if (st < st_last) {
            STAGE(buf ^ 1, st + 1);                       // prefetch next tile
            asm volatile("s_waitcnt vmcnt(32)" ::: "memory");  // current tile done
        } else {
            asm volatile("s_waitcnt vmcnt(0)" ::: "memory");
        }

        f32x4 sa0 = (f32x4){0.f, 0.f, 0.f, 0.f};
        f32x4 sa1 = (f32x4){0.f, 0.f, 0.f, 0.f};
        #pragma unroll
        for (int c = 0; c < 8; ++c) {
            int sl = (c * 4 + lk) ^ (q & 7);
            short8 kf0 = *(const short8*)&K_s[buf][q * 256 + sl * 8];
            short8 kf1 = *(const short8*)&K_s[buf][(16 + q) * 256 + sl * 8];
            sa0 = __builtin_amdgcn_mfma_f32_16x16x32_bf16(kf0, qf[c], sa0, 0, 0, 0);
            sa1 = __builtin_amdgcn_mfma_f32_16x16x32_bf16(kf1, qf[c], sa1, 0, 0, 0);
        }

        float sv0[4], sv1[4];
        #pragma unroll
        for (int j = 0; j < 4; ++j) { sv0[j] = sa0[j] * 0.0625f; sv1[j] = sa1[j] * 0.0625f; }
        if (st == st_last) {
            int qgl = qbase + q;
            #pragma unroll
            for (int j = 0; j < 4; ++j) {
                if (st * 32 + lk * 4 + j > qgl)      sv0[j] = -1e30f;
                if (st * 32 + 16 + lk * 4 + j > qgl) sv1[j] = -1e30f;
            }
        }

        float tm = sv0[0];
        #pragma unroll
        for (int j = 1; j < 4; ++j) tm = fmaxf(tm, sv0[j]);
        #pragma unroll
        for (int j = 0; j < 4; ++j) tm = fmaxf(tm, sv1[j]);
        tm = fmaxf(tm, __shfl_xor(tm, 16));
        tm = fmaxf(tm, __shfl_xor(tm, 32));
        float mn = fmaxf(m_run, tm);
        float alpha = __expf(m_run - mn);
        float p0[4], p1[4], ts = 0.f;
        #pragma unroll
        for (int j = 0; j < 4; ++j) {
            p0[j] = __expf(sv0[j] - mn);
            p1[j] = __expf(sv1[j] - mn);
            ts += p0[j] + p1[j];
        }
        ts += __shfl_xor(ts, 16);
        ts += __shfl_xor(ts, 32);
        l_run = l_run * alpha + ts;
        m_run = mn;

        #pragma unroll
        for (int i = 0; i < 16; ++i) {
            o[i][0] *= alpha; o[i][1] *= alpha; o[i][2] *= alpha; o[i][3] *= alpha;
        }

        unsigned c0 = pk2(p0[0], p0[1]), c1 = pk2(p0[2], p0[3]);
        unsigned d0 = pk2(p1[0], p1[1]), d1 = pk2(p1[2], p1[3]);
        int sA = q + 32 * (lk & 1);
        int sB = sA + 16;
        unsigned a0c = __shfl(c0, sA), a1c = __shfl(c1, sA);
        unsigned b0c = __shfl(c0, sB), b1c = __shfl(c1, sB);
        unsigned a0d = __shfl(d0, sA), a1d = __shfl(d1, sA);
        unsigned b0d = __shfl(d0, sB), b1d = __shfl(d1, sB);
        bool hi = (lk >> 1) != 0;
        union { short8 s; unsigned u[4]; } pb;
        pb.u[0] = hi ? a0d : a0c;
        pb.u[1] = hi ? a1d : a1c;
        pb.u[2] = hi ? b0d : b0c;
        pb.u[3] = hi ? b1d : b1c;

        #pragma unroll
        for (int eb = 0; eb < 16; ++eb) {
            int er = eb * 16 + q;
            int sl = lk ^ (er & 3);
            short8 vf = *(const short8*)&V_s[buf][er * 32 + sl * 8];
            o[eb] = __builtin_amdgcn_mfma_f32_16x16x32_bf16(vf, pb.s, o[eb], 0, 0, 0);
        }
        buf ^= 1;
    }

    float inv_l = 1.f / l_run;
    ushort* orow = ao + (size_t)(b * TSEQ + qbase + q) * EMB;
    #pragma unroll
    for (int eb = 0; eb < 16; ++eb) {
        uint2 w;
        w.x = pk2(o[eb][0] * inv_l, o[eb][1] * inv_l);
        w.y = pk2(o[eb][2] * inv_l, o[eb][3] * inv_l);
        *(uint2*)&orow[eb * 16 + lk * 4] = w;
    }
}

// ---------------- logits GEMM: R4 2-phase loop + swapped mfma -> float4 nt stores ----------------
// mfma(b,a): D rows = vocab-col (reg quad), D cols = token (lane&15). Each lane's f32x4 =
// 4 consecutive vocab cols of one token -> global_store_dwordx4 (16/thread vs 64 scalar).
__global__ __launch_bounds__(256) void k_gemm(const ushort* __restrict__ A,
                                              const ushort* __restrict__ Bt,
                                              const float* __restrict__ lmb,
                                              float* __restrict__ C,
                                              float2* __restrict__ part) {
    __shared__ ushort As[2][128 * 64];
    __shared__ ushort Bs[2][128 * 64];
    __shared__ float fbM[128], fbS[128];

    int linear = blockIdx.x;
    int swz = (linear & 7) * 1000 + (linear >> 3);   // bijective XCD swizzle (8000%8==0)
    int m0 = (swz & 31) * 128;
    int nb = swz >> 5;
    int n0 = nb * 128;

    int tid = threadIdx.x;
    int lane = tid & 63, wave = tid >> 6;
    int wm = wave >> 1, wn = wave & 1;
    int lr = lane >> 3, cc = lane & 7;
    int lrow = lane & 15, lk = lane >> 4;

    auto STAGE = [&](int bufi, int k0) {
        #pragma unroll
        for (int j = 0; j < 4; ++j) {
            int rbase = j * 32 + wave * 8;
            int row = rbase + lr;
            int cs = cc ^ (row & 7);
            const ushort* ga = A + (size_t)(m0 + row) * EMB + k0 + cs * 8;
            const ushort* gb = Bt + (size_t)(n0 + row) * EMB + k0 + cs * 8;
            __builtin_amdgcn_global_load_lds(
                (const __attribute__((address_space(1))) void*)ga,
                (__attribute__((address_space(3))) void*)&As[bufi][rbase * 64], 16, 0, 0);
            __builtin_amdgcn_global_load_lds(
                (const __attribute__((address_space(1))) void*)gb,
                (__attribute__((address_space(3))) void*)&Bs[bufi][rbase * 64], 16, 0, 0);
        }
    };

    f32x4 acc[4][4];
    #pragma unroll
    for (int i = 0; i < 4; ++i)
        #pragma unroll
        for (int j = 0; j < 4; ++j)
            acc[i][j] = (f32x4){0.f, 0.f, 0.f, 0.f};

    STAGE(0, 0);
    asm volatile("s_waitcnt vmcnt(0)" ::: "memory");
    __syncthreads();

    #pragma unroll
    for (int t = 0; t < 4; ++t) {
        if (t < 3) STAGE((t + 1) & 1, (t + 1) * 64);   // prefetch next, in flight under compute
        const ushort* Ab = As[t & 1];
        const ushort* Bb = Bs[t & 1];
        #pragma unroll
        for (int kk = 0; kk < 2; ++kk) {
            short8 a[4], b[4];
            #pragma unroll
            for (int m = 0; m < 4; ++m) {
                int row = wm * 64 + m * 16 + lrow;
                int c2 = (kk * 4 + lk) ^ (row & 7);
                a[m] = *(const short8*)&Ab[row * 64 + c2 * 8];
            }
            #pragma unroll
            for (int n = 0; n < 4; ++n) {
                int row = wn * 64 + n * 16 + lrow;
                int c2 = (kk * 4 + lk) ^ (row & 7);
                b[n] = *(const short8*)&Bb[row * 64 + c2 * 8];
            }
            #pragma unroll
            for (int m = 0; m < 4; ++m)
                #pragma unroll
                for (int n = 0; n < 4; ++n)
                    acc[m][n] = __builtin_amdgcn_mfma_f32_16x16x32_bf16(
                        b[n], a[m], acc[m][n], 0, 0, 0);   // SWAPPED
        }
        if (t < 3) {
            asm volatile("s_waitcnt vmcnt(0)" ::: "memory");
            __syncthreads();
        }
    }

    // bias: 4 consecutive vocab cols per lane per n
    f32x4 bias4[4];
    #pragma unroll
    for (int n = 0; n < 4; ++n)
        bias4[n] = *(const f32x4*)&lmb[n0 + wn * 64 + n * 16 + lk * 4];

    // write logits: token = lane&15-based row; 16B nontemporal vector stores
    #pragma unroll
    for (int m = 0; m < 4; ++m) {
        int token = m0 + wm * 64 + m * 16 + lrow;
        #pragma unroll
        for (int n = 0; n < 4; ++n) {
            f32x4 v = acc[m][n] + bias4[n];
            __builtin_nontemporal_store(v,
                (f32x4*)&C[(size_t)token * VOCAB + n0 + wn * 64 + n * 16 + lk * 4]);
        }
    }

    // per-token logsumexp partial: 16 lane-local values, then combine lk-groups (xor 16,32)
    float pM[4], pS[4];
    #pragma unroll
    for (int m = 0; m < 4; ++m) {
        float v[16];
        #pragma unroll
        for (int n = 0; n < 4; ++n)
            #pragma unroll
            for (int j = 0; j < 4; ++j)
                v[n * 4 + j] = acc[m][n][j] + bias4[n][j];
        float tM = v[0];
        #pragma unroll
        for (int i = 1; i < 16; ++i) tM = fmaxf(tM, v[i]);
        float tS = 0.f;
        #pragma unroll
        for (int i = 0; i < 16; ++i) tS += __expf(v[i] - tM);
        #pragma unroll
        for (int off = 16; off <= 32; off <<= 1) {
            float oM = __shfl_xor(tM, off);
            float oS = __shfl_xor(tS, off);
            float nM = fmaxf(tM, oM);
            tS = tS * __expf(tM - nM) + oS * __expf(oM - nM);
            tM = nM;
        }
        pM[m] = tM; pS[m] = tS;
    }
    // combine the two wn halves via tiny LDS; raw barrier + lgkmcnt only (nt stores in flight)
    if (wn == 0 && lk == 0) {
        #pragma unroll
        for (int m = 0; m < 4; ++m) {
            int r = wm * 64 + m * 16 + lrow;
            fbM[r] = pM[m]; fbS[r] = pS[m];
        }
    }
    asm volatile("s_waitcnt lgkmcnt(0)" ::: "memory");
    __builtin_amdgcn_s_barrier();
    asm volatile("" ::: "memory");
    if (wn == 1 && lk == 0) {
        #pragma unroll
        for (int m = 0; m < 4; ++m) {
            int r = wm * 64 + m * 16 + lrow;
            float oM = fbM[r], oS = fbS[r];
            float tM = pM[m], tS = pS[m];
            float nM = fmaxf(tM, oM);
            float nS = tS * __expf(tM - nM) + oS * __expf(oM - nM);
            part[(size_t)(m0 + r) * NBLKN + nb] = make_float2(nM, nS);
        }
    }
}

// ---------------- loss reduce over partials ----------------
__global__ __launch_bounds__(256) void k_reduce(const float2* __restrict__ part,
                                                const float* __restrict__ logits,
                                                const int* __restrict__ tgt,
                                                float* __restrict__ loss) {
    int row = blockIdx.x;
    int tid = threadIdx.x;
    float M = -1e30f, S = 0.f;
    for (int i = tid; i < NBLKN; i += 256) {
        float2 p = part[(size_t)row * NBLKN + i];
        float nM = fmaxf(M, p.x);
        S = S * __expf(M - nM) + p.y * __expf(p.x - nM);
        M = nM;
    }
    #pragma unroll
    for (int off = 1; off < 64; off <<= 1) {
        float oM = __shfl_xor(M, off);
        float oS = __shfl_xor(S, off);
        float nM = fmaxf(M, oM);
        S = S * __expf(M - nM) + oS * __expf(oM - nM);
        M = nM;
    }
    __shared__ float wm[4], ws[4];
    int lane = tid & 63, wave = tid >> 6;
    if (lane == 0) { wm[wave] = M; ws[wave] = S; }
    __syncthreads();
    if (tid == 0) {
        float fM = wm[0], fS = ws[0];
        #pragma unroll
        for (int w = 1; w < 4; ++w) {
            float nM = fmaxf(fM, wm[w]);
            fS = fS * __expf(fM - nM) + ws[w] * __expf(wm[w] - nM);
            fM = nM;
        }
        float lse = fM + __logf(fS);
        float tl = logits[(size_t)row * VOCAB + tgt[row]];
        atomicAdd(loss, (lse - tl) * (1.0f / 4096.0f));
    }
}

extern "C" void kernel_launch(void* const* d_in, const int* in_sizes, int n_in,
                              void* d_out, int out_size, void* d_ws, size_t ws_size,
                              hipStream_t stream) {
    (void)in_sizes; (void)n_in; (void)ws_size;
    const int*   idx     = (const int*)d_in[0];
    const int*   targets = (const int*)d_in[1];
    const float* tok     = (const float*)d_in[2];
    const float* pos     = (const float*)d_in[3];
    const float* Wk      = (const float*)d_in[4];
    const float* Wq      = (const float*)d_in[5];
    const float* Wv      = (const float*)d_in[6];
    const float* lmW     = (const float*)d_in[7];
    const float* lmb     = (const float*)d_in[8];

    float* logits = (float*)d_out;
    float* loss   = logits + (size_t)out_size - 1;

    const size_t MB = 1u << 20;
    char* w = (char*)d_ws;
    ushort* Wt3  = (ushort*)(w);                 // 384 KB
    ushort* xb   = (ushort*)(w + MB / 2);        // 2 MB
    ushort* qb   = (ushort*)(w + 5 * MB / 2);    // 2 MB
    ushort* kbf  = (ushort*)(w + 9 * MB / 2);    // 2 MB
    ushort* vt   = (ushort*)(w + 13 * MB / 2);   // 2 MB
    ushort* ao   = (ushort*)(w + 17 * MB / 2);   // 2 MB
    ushort* Wt   = (ushort*)(w + 21 * MB / 2);   // 16 MB
    float2* part = (float2*)(w + 28 * MB);       // 8 MB

    hipMemsetAsync(loss, 0, sizeof(float), stream);
    k_conv<<<dim3(1024, 8), 256, 0, stream>>>(lmW, Wq, Wk, Wv, Wt, Wt3);
    k_embed<<<NROWS, 256, 0, stream>>>(idx, tok, pos, xb);
    k_qkv_mm<<<dim3(NROWS / 128, EMB / 128, 3), 256, 0, stream>>>(xb, Wt3, qb, kbf, vt);
    k_attn<<<256, 64, 0, stream>>>(qb, kbf, vt, ao);
    k_gemm<<<8000, 256, 0, stream>>>(ao, Wt, lmb, logits, part);
    k_reduce<<<NROWS, 256, 0, stream>>>(part, logits, targets, loss);
}

// Round 10
// 321.207 us; speedup vs baseline: 3.2702x; 1.0054x over previous
//
#include <hip/hip_runtime.h>
#include <hip/hip_bf16.h>
#include <math.h>

#define VOCAB 32000
#define EMB   256
#define TSEQ  1024
#define NROWS 4096
#define NBLKN 250   // VOCAB/128

typedef __attribute__((ext_vector_type(8))) short short8;
typedef __attribute__((ext_vector_type(4))) float f32x4;

static __device__ __forceinline__ unsigned short bfb(float x) {
    __hip_bfloat16 h = __float2bfloat16(x);
    return *(unsigned short*)&h;
}
static __device__ __forceinline__ unsigned pk2(float a, float b) {
    return (unsigned)bfb(a) | ((unsigned)bfb(b) << 16);
}

// ---------------- fused pre-pass: lm_W / Wq / Wk / Wv transpose+convert, embed ----------------
// blocks 0..7999: lm_W -> Wt ; 8000..8191: Wq/Wk/Wv -> Wt3 ; 8192..12287: embed
__global__ __launch_bounds__(256) void k_pre(const float* __restrict__ lmW,
                                             const float* __restrict__ Wq,
                                             const float* __restrict__ Wk,
                                             const float* __restrict__ Wv,
                                             const int* __restrict__ idx,
                                             const float* __restrict__ tok,
                                             const float* __restrict__ pos,
                                             ushort* __restrict__ Wt,
                                             ushort* __restrict__ Wt3,
                                             ushort* __restrict__ xb) {
    int bx = blockIdx.x;
    if (bx >= 8192) {                      // embed
        int row = bx - 8192;
        int t = row & (TSEQ - 1);
        int token = idx[row];
        int e = threadIdx.x;
        xb[row * EMB + e] = bfb(tok[token * EMB + e] + pos[t * EMB + e]);
        return;
    }
    __shared__ float T[32][33];
    const float* W; ushort* out; int n0, k0, ncols;
    if (bx < 8000) {
        W = lmW; out = Wt; n0 = (bx >> 3) * 32; k0 = (bx & 7) * 32; ncols = VOCAB;
    } else {
        int xi = bx - 8000;                // 0..191
        int z = xi >> 6, rem = xi & 63;
        W = (z == 0) ? Wq : (z == 1) ? Wk : Wv;
        out = Wt3 + (size_t)z * EMB * EMB;
        n0 = (rem >> 3) * 32; k0 = (rem & 7) * 32; ncols = EMB;
    }
    int tx = threadIdx.x & 31, ty = threadIdx.x >> 5;
    #pragma unroll
    for (int i = 0; i < 4; ++i) {
        int kk = ty + 8 * i;
        T[kk][tx] = W[(size_t)(k0 + kk) * ncols + n0 + tx];
    }
    __syncthreads();
    #pragma unroll
    for (int i = 0; i < 4; ++i) {
        int r = ty + 8 * i;
        out[(size_t)(n0 + r) * EMB + k0 + tx] = bfb(T[tx][r]);
    }
}

// ---------------- qkv MFMA GEMM (unchanged from R9) ----------------
__global__ __launch_bounds__(256) void k_qkv_mm(const ushort* __restrict__ A,
                                                const ushort* __restrict__ Wt3,
                                                ushort* __restrict__ qb,
                                                ushort* __restrict__ kbf,
                                                ushort* __restrict__ vt) {
    __shared__ ushort As[128 * 64];
    __shared__ ushort Bs[128 * 64];

    int z = blockIdx.z;
    const ushort* Bt = Wt3 + (size_t)z * EMB * EMB;

    int m0 = blockIdx.x * 128, n0 = blockIdx.y * 128;
    int tid = threadIdx.x;
    int lane = tid & 63, wave = tid >> 6;
    int wm = wave >> 1, wn = wave & 1;
    int lr = lane >> 3, cc = lane & 7;
    int lrow = lane & 15, lk = lane >> 4;

    f32x4 acc[4][4];
    #pragma unroll
    for (int i = 0; i < 4; ++i)
        #pragma unroll
        for (int j = 0; j < 4; ++j)
            acc[i][j] = (f32x4){0.f, 0.f, 0.f, 0.f};

    for (int k0 = 0; k0 < EMB; k0 += 64) {
        #pragma unroll
        for (int j = 0; j < 4; ++j) {
            int rbase = j * 32 + wave * 8;
            int row = rbase + lr;
            int cs = cc ^ (row & 7);
            const ushort* ga = A + (size_t)(m0 + row) * EMB + k0 + cs * 8;
            const ushort* gb = Bt + (size_t)(n0 + row) * EMB + k0 + cs * 8;
            __builtin_amdgcn_global_load_lds(
                (const __attribute__((address_space(1))) void*)ga,
                (__attribute__((address_space(3))) void*)&As[rbase * 64], 16, 0, 0);
            __builtin_amdgcn_global_load_lds(
                (const __attribute__((address_space(1))) void*)gb,
                (__attribute__((address_space(3))) void*)&Bs[rbase * 64], 16, 0, 0);
        }
        __syncthreads();
        #pragma unroll
        for (int kk = 0; kk < 2; ++kk) {
            short8 a[4], b[4];
            #pragma unroll
            for (int m = 0; m < 4; ++m) {
                int row = wm * 64 + m * 16 + lrow;
                int c2 = (kk * 4 + lk) ^ (row & 7);
                a[m] = *(const short8*)&As[row * 64 + c2 * 8];
            }
            #pragma unroll
            for (int n = 0; n < 4; ++n) {
                int row = wn * 64 + n * 16 + lrow;
                int c2 = (kk * 4 + lk) ^ (row & 7);
                b[n] = *(const short8*)&Bs[row * 64 + c2 * 8];
            }
            if (z < 2) {
                #pragma unroll
                for (int m = 0; m < 4; ++m)
                    #pragma unroll
                    for (int n = 0; n < 4; ++n)
                        acc[m][n] = __builtin_amdgcn_mfma_f32_16x16x32_bf16(
                            b[n], a[m], acc[m][n], 0, 0, 0);   // swapped
            } else {
                #pragma unroll
                for (int m = 0; m < 4; ++m)
                    #pragma unroll
                    for (int n = 0; n < 4; ++n)
                        acc[m][n] = __builtin_amdgcn_mfma_f32_16x16x32_bf16(
                            a[m], b[n], acc[m][n], 0, 0, 0);
            }
        }
        __syncthreads();
    }

    if (z < 2) {
        ushort* out = (z == 0) ? qb : kbf;
        #pragma unroll
        for (int m = 0; m < 4; ++m) {
            int token = m0 + wm * 64 + m * 16 + lrow;
            #pragma unroll
            for (int n = 0; n < 4; ++n) {
                uint2 w;
                w.x = pk2(acc[m][n][0], acc[m][n][1]);
                w.y = pk2(acc[m][n][2], acc[m][n][3]);
                *(uint2*)&out[(size_t)token * EMB + n0 + wn * 64 + n * 16 + lk * 4] = w;
            }
        }
    } else {
        #pragma unroll
        for (int n = 0; n < 4; ++n) {
            int e = n0 + wn * 64 + n * 16 + lrow;
            #pragma unroll
            for (int m = 0; m < 4; ++m) {
                int row = m0 + wm * 64 + m * 16 + lk * 4;
                int bb = row >> 10, rr = row & 1023;
                uint2 w;
                w.x = pk2(acc[m][n][0], acc[m][n][1]);
                w.y = pk2(acc[m][n][2], acc[m][n][3]);
                *(uint2*)&vt[((size_t)bb * EMB + e) * TSEQ + rr] = w;
            }
        }
    }
}

// ---------------- MFMA flash attention: 32 blocks x 8 waves, shared K/V staging ----------------
// Block = one 128-row group (b, g). Wave w owns rows qbase = g*128 + w*16.
// All waves share K/V tiles (same st range); staging split 8 ways (4 insts/wave/tile).
// Counted vmcnt(4) + raw s_barrier keeps dbuf prefetch in flight across barriers.
__global__ __launch_bounds__(512) void k_attn(const ushort* __restrict__ qg,
                                              const ushort* __restrict__ kg,
                                              const ushort* __restrict__ vt,
                                              ushort* __restrict__ ao) {
    __shared__ ushort K_s[2][32 * 256];
    __shared__ ushort V_s[2][256 * 32];

    int b = blockIdx.x >> 3;
    int g = blockIdx.x & 7;
    int wave = threadIdx.x >> 6;
    int lane = threadIdx.x & 63;
    int qbase = g * 128 + wave * 16;
    int q = lane & 15, lk = lane >> 4;

    const ushort* qrow = qg + (size_t)(b * TSEQ + qbase + q) * EMB;
    short8 qf[8];
    #pragma unroll
    for (int c = 0; c < 8; ++c)
        qf[c] = *(const short8*)&qrow[c * 32 + lk * 8];

    f32x4 o[16];
    #pragma unroll
    for (int i = 0; i < 16; ++i) o[i] = (f32x4){0.f, 0.f, 0.f, 0.f};
    float m_run = -1e30f, l_run = 0.f;

    // staging: wave w does K-insts {2w, 2w+1} and V-insts {2w, 2w+1} -> 4 insts/wave/tile
    auto STAGE = [&](int buf, int st) {
        const ushort* kbase = kg + (size_t)(b * TSEQ + st * 32) * EMB;
        #pragma unroll
        for (int i = 0; i < 2; ++i) {
            int t = wave * 2 + i;
            int r = t * 2 + (lane >> 5);
            int slot = lane & 31;
            int chunk = slot ^ (r & 7);
            const ushort* src = kbase + r * EMB + chunk * 8;
            __builtin_amdgcn_global_load_lds(
                (const __attribute__((address_space(1))) void*)src,
                (__attribute__((address_space(3))) void*)&K_s[buf][t * 512], 16, 0, 0);
        }
        #pragma unroll
        for (int i = 0; i < 2; ++i) {
            int t = wave * 2 + i;
            int e = t * 16 + (lane >> 2);
            int slot = lane & 3;
            int chunk = slot ^ (e & 3);
            const ushort* src = vt + ((size_t)b * EMB + e) * TSEQ + st * 32 + chunk * 8;
            __builtin_amdgcn_global_load_lds(
                (const __attribute__((address_space(1))) void*)src,
                (__attribute__((address_space(3))) void*)&V_s[buf][t * 512], 16, 0, 0);
        }
    };

    int wlast = (qbase + 15) >> 5;        // per-wave causal tile limit
    int glast = (g * 128 + 127) >> 5;     // block-uniform last tile (= 4g+3)
    STAGE(0, 0);
    int buf = 0;

    for (int st = 0; st <= glast; ++st) {
        if (st < glast) {
            STAGE(buf ^ 1, st + 1);                              // +4 in flight
            asm volatile("s_waitcnt vmcnt(4)" ::: "memory");     // tile st landed (ours)
        } else {
            asm volatile("s_waitcnt vmcnt(0)" ::: "memory");
        }
        __builtin_amdgcn_s_barrier();                            // all waves' tile st landed

        if (st <= wlast) {
            f32x4 sa0 = (f32x4){0.f, 0.f, 0.f, 0.f};
            f32x4 sa1 = (f32x4){0.f, 0.f, 0.f, 0.f};
            #pragma unroll
            for (int c = 0; c < 8; ++c) {
                int sl = (c * 4 + lk) ^ (q & 7);
                short8 kf0 = *(const short8*)&K_s[buf][q * 256 + sl * 8];
                short8 kf1 = *(const short8*)&K_s[buf][(16 + q) * 256 + sl * 8];
                sa0 = __builtin_amdgcn_mfma_f32_16x16x32_bf16(kf0, qf[c], sa0, 0, 0, 0);
                sa1 = __builtin_amdgcn_mfma_f32_16x16x32_bf16(kf1, qf[c], sa1, 0, 0, 0);
            }

            float sv0[4], sv1[4];
            #pragma unroll
            for (int j = 0; j < 4; ++j) { sv0[j] = sa0[j] * 0.0625f; sv1[j] = sa1[j] * 0.0625f; }
            if (st == wlast) {
                int qgl = qbase + q;
                #pragma unroll
                for (int j = 0; j < 4; ++j) {
                    if (st * 32 + lk * 4 + j > qgl)      sv0[j] = -1e30f;
                    if (st * 32 + 16 + lk * 4 + j > qgl) sv1[j] = -1e30f;
                }
            }

            float tm = sv0[0];
            #pragma unroll
            for (int j = 1; j < 4; ++j) tm = fmaxf(tm, sv0[j]);
            #pragma unroll
            for (int j = 0; j < 4; ++j) tm = fmaxf(tm, sv1[j]);
            tm = fmaxf(tm, __shfl_xor(tm, 16));
            tm = fmaxf(tm, __shfl_xor(tm, 32));
            float mn = fmaxf(m_run, tm);
            float alpha = __expf(m_run - mn);
            float p0[4], p1[4], ts = 0.f;
            #pragma unroll
            for (int j = 0; j < 4; ++j) {
                p0[j] = __expf(sv0[j] - mn);
                p1[j] = __expf(sv1[j] - mn);
                ts += p0[j] + p1[j];
            }
            ts += __shfl_xor(ts, 16);
            ts += __shfl_xor(ts, 32);
            l_run = l_run * alpha + ts;
            m_run = mn;

            #pragma unroll
            for (int i = 0; i < 16; ++i) {
                o[i][0] *= alpha; o[i][1] *= alpha; o[i][2] *= alpha; o[i][3] *= alpha;
            }

            unsigned c0 = pk2(p0[0], p0[1]), c1 = pk2(p0[2], p0[3]);
            unsigned d0 = pk2(p1[0], p1[1]), d1 = pk2(p1[2], p1[3]);
            int sA = q + 32 * (lk & 1);
            int sB = sA + 16;
            unsigned a0c = __shfl(c0, sA), a1c = __shfl(c1, sA);
            unsigned b0c = __shfl(c0, sB), b1c = __shfl(c1, sB);
            unsigned a0d = __shfl(d0, sA), a1d = __shfl(d1, sA);
            unsigned b0d = __shfl(d0, sB), b1d = __shfl(d1, sB);
            bool hi = (lk >> 1) != 0;
            union { short8 s; unsigned u[4]; } pb;
            pb.u[0] = hi ? a0d : a0c;
            pb.u[1] = hi ? a1d : a1c;
            pb.u[2] = hi ? b0d : b0c;
            pb.u[3] = hi ? b1d : b1c;

            #pragma unroll
            for (int eb = 0; eb < 16; ++eb) {
                int er = eb * 16 + q;
                int sl = lk ^ (er & 3);
                short8 vf = *(const short8*)&V_s[buf][er * 32 + sl * 8];
                o[eb] = __builtin_amdgcn_mfma_f32_16x16x32_bf16(vf, pb.s, o[eb], 0, 0, 0);
            }
        }
        __builtin_amdgcn_s_barrier();    // all reads of buf done before next overwrite
        buf ^= 1;
    }

    float inv_l = 1.f / l_run;
    ushort* orow = ao + (size_t)(b * TSEQ + qbase + q) * EMB;
    #pragma unroll
    for (int eb = 0; eb < 16; ++eb) {
        uint2 w;
        w.x = pk2(o[eb][0] * inv_l, o[eb][1] * inv_l);
        w.y = pk2(o[eb][2] * inv_l, o[eb][3] * inv_l);
        *(uint2*)&orow[eb * 16 + lk * 4] = w;
    }
}

// ---------------- logits GEMM: BK=32 dbuf (33 KB LDS -> 3-4 blocks/CU), R9 loop shape ----------------
__global__ __launch_bounds__(256) void k_gemm(const ushort* __restrict__ A,
                                              const ushort* __restrict__ Bt,
                                              const float* __restrict__ lmb,
                                              float* __restrict__ C,
                                              float2* __restrict__ part) {
    __shared__ ushort As[2][128 * 32];   // 8 KB each
    __shared__ ushort Bs[2][128 * 32];
    __shared__ float fbM[128], fbS[128];

    int linear = blockIdx.x;
    int swz = (linear & 7) * 1000 + (linear >> 3);   // bijective XCD swizzle (8000%8==0)
    int m0 = (swz & 31) * 128;
    int nb = swz >> 5;
    int n0 = nb * 128;

    int tid = threadIdx.x;
    int lane = tid & 63, wave = tid >> 6;
    int wm = wave >> 1, wn = wave & 1;
    int lrow = lane & 15, lk = lane >> 4;

    // stage: per matrix 8 insts (16 rows x 64B each) over 4 waves = 2/wave; +2 for B = 4/wave
    auto STAGE = [&](int bufi, int t) {
        int k0 = t * 32;
        #pragma unroll
        for (int i = 0; i < 2; ++i) {
            int rbase = i * 64 + wave * 16;
            int row = rbase + (lane >> 2);
            int cs = (lane & 3) ^ (row & 3);
            const ushort* ga = A + (size_t)(m0 + row) * EMB + k0 + cs * 8;
            const ushort* gb = Bt + (size_t)(n0 + row) * EMB + k0 + cs * 8;
            __builtin_amdgcn_global_load_lds(
                (const __attribute__((address_space(1))) void*)ga,
                (__attribute__((address_space(3))) void*)&As[bufi][rbase * 32], 16, 0, 0);
            __builtin_amdgcn_global_load_lds(
                (const __attribute__((address_space(1))) void*)gb,
                (__attribute__((address_space(3))) void*)&Bs[bufi][rbase * 32], 16, 0, 0);
        }
    };

    f32x4 acc[4][4];
    #pragma unroll
    for (int i = 0; i < 4; ++i)
        #pragma unroll
        for (int j = 0; j < 4; ++j)
            acc[i][j] = (f32x4){0.f, 0.f, 0.f, 0.f};

    STAGE(0, 0);
    asm volatile("s_waitcnt vmcnt(0)" ::: "memory");
    __syncthreads();

    #pragma unroll
    for (int t = 0; t < 8; ++t) {
        if (t < 7) STAGE((t + 1) & 1, t + 1);     // prefetch next, in flight under compute
        const ushort* Ab = As[t & 1];
        const ushort* Bb = Bs[t & 1];
        short8 a[4], b[4];
        #pragma unroll
        for (int m = 0; m < 4; ++m) {
            int row = wm * 64 + m * 16 + lrow;
            int sl = lk ^ (row & 3);
            a[m] = *(const short8*)&Ab[row * 32 + sl * 8];
        }
        #pragma unroll
        for (int n = 0; n < 4; ++n) {
            int row = wn * 64 + n * 16 + lrow;
            int sl = lk ^ (row & 3);
            b[n] = *(const short8*)&Bb[row * 32 + sl * 8];
        }
        #pragma unroll
        for (int m = 0; m < 4; ++m)
            #pragma unroll
            for (int n = 0; n < 4; ++n)
                acc[m][n] = __builtin_amdgcn_mfma_f32_16x16x32_bf16(
                    b[n], a[m], acc[m][n], 0, 0, 0);   // SWAPPED
        if (t < 7) {
            asm volatile("s_waitcnt vmcnt(0)" ::: "memory");
            __syncthreads();
        }
    }

    // bias: 4 consecutive vocab cols per lane per n
    f32x4 bias4[4];
    #pragma unroll
    for (int n = 0; n < 4; ++n)
        bias4[n] = *(const f32x4*)&lmb[n0 + wn * 64 + n * 16 + lk * 4];

    // write logits: 16B nontemporal vector stores
    #pragma unroll
    for (int m = 0; m < 4; ++m) {
        int token = m0 + wm * 64 + m * 16 + lrow;
        #pragma unroll
        for (int n = 0; n < 4; ++n) {
            f32x4 v = acc[m][n] + bias4[n];
            __builtin_nontemporal_store(v,
                (f32x4*)&C[(size_t)token * VOCAB + n0 + wn * 64 + n * 16 + lk * 4]);
        }
    }

    // per-token logsumexp partial
    float pM[4], pS[4];
    #pragma unroll
    for (int m = 0; m < 4; ++m) {
        float v[16];
        #pragma unroll
        for (int n = 0; n < 4; ++n)
            #pragma unroll
            for (int j = 0; j < 4; ++j)
                v[n * 4 + j] = acc[m][n][j] + bias4[n][j];
        float tM = v[0];
        #pragma unroll
        for (int i = 1; i < 16; ++i) tM = fmaxf(tM, v[i]);
        float tS = 0.f;
        #pragma unroll
        for (int i = 0; i < 16; ++i) tS += __expf(v[i] - tM);
        #pragma unroll
        for (int off = 16; off <= 32; off <<= 1) {
            float oM = __shfl_xor(tM, off);
            float oS = __shfl_xor(tS, off);
            float nM = fmaxf(tM, oM);
            tS = tS * __expf(tM - nM) + oS * __expf(oM - nM);
            tM = nM;
        }
        pM[m] = tM; pS[m] = tS;
    }
    if (wn == 0 && lk == 0) {
        #pragma unroll
        for (int m = 0; m < 4; ++m) {
            int r = wm * 64 + m * 16 + lrow;
            fbM[r] = pM[m]; fbS[r] = pS[m];
        }
    }
    asm volatile("s_waitcnt lgkmcnt(0)" ::: "memory");
    __builtin_amdgcn_s_barrier();
    asm volatile("" ::: "memory");
    if (wn == 1 && lk == 0) {
        #pragma unroll
        for (int m = 0; m < 4; ++m) {
            int r = wm * 64 + m * 16 + lrow;
            float oM = fbM[r], oS = fbS[r];
            float tM = pM[m], tS = pS[m];
            float nM = fmaxf(tM, oM);
            float nS = tS * __expf(tM - nM) + oS * __expf(oM - nM);
            part[(size_t)(m0 + r) * NBLKN + nb] = make_float2(nM, nS);
        }
    }
}

// ---------------- loss reduce over partials ----------------
__global__ __launch_bounds__(256) void k_reduce(const float2* __restrict__ part,
                                                const float* __restrict__ logits,
                                                const int* __restrict__ tgt,
                                                float* __restrict__ loss) {
    int row = blockIdx.x;
    int tid = threadIdx.x;
    float M = -1e30f, S = 0.f;
    for (int i = tid; i < NBLKN; i += 256) {
        float2 p = part[(size_t)row * NBLKN + i];
        float nM = fmaxf(M, p.x);
        S = S * __expf(M - nM) + p.y * __expf(p.x - nM);
        M = nM;
    }
    #pragma unroll
    for (int off = 1; off < 64; off <<= 1) {
        float oM = __shfl_xor(M, off);
        float oS = __shfl_xor(S, off);
        float nM = fmaxf(M, oM);
        S = S * __expf(M - nM) + oS * __expf(oM - nM);
        M = nM;
    }
    __shared__ float wm[4], ws[4];
    int lane = tid & 63, wave = tid >> 6;
    if (lane == 0) { wm[wave] = M; ws[wave] = S; }
    __syncthreads();
    if (tid == 0) {
        float fM = wm[0], fS = ws[0];
        #pragma unroll
        for (int w = 1; w < 4; ++w) {
            float nM = fmaxf(fM, wm[w]);
            fS = fS * __expf(fM - nM) + ws[w] * __expf(wm[w] - nM);
            fM = nM;
        }
        float lse = fM + __logf(fS);
        float tl = logits[(size_t)row * VOCAB + tgt[row]];
        atomicAdd(loss, (lse - tl) * (1.0f / 4096.0f));
    }
}

extern "C" void kernel_launch(void* const* d_in, const int* in_sizes, int n_in,
                              void* d_out, int out_size, void* d_ws, size_t ws_size,
                              hipStream_t stream) {
    (void)in_sizes; (void)n_in; (void)ws_size;
    const int*   idx     = (const int*)d_in[0];
    const int*   targets = (const int*)d_in[1];
    const float* tok     = (const float*)d_in[2];
    const float* pos     = (const float*)d_in[3];
    const float* Wk      = (const float*)d_in[4];
    const float* Wq      = (const float*)d_in[5];
    const float* Wv      = (const float*)d_in[6];
    const float* lmW     = (const float*)d_in[7];
    const float* lmb     = (const float*)d_in[8];

    float* logits = (float*)d_out;
    float* loss   = logits + (size_t)out_size - 1;

    const size_t MB = 1u << 20;
    char* w = (char*)d_ws;
    ushort* Wt3  = (ushort*)(w);                 // 384 KB
    ushort* xb   = (ushort*)(w + MB / 2);        // 2 MB
    ushort* qb   = (ushort*)(w + 5 * MB / 2);    // 2 MB
    ushort* kbf  = (ushort*)(w + 9 * MB / 2);    // 2 MB
    ushort* vt   = (ushort*)(w + 13 * MB / 2);   // 2 MB
    ushort* ao   = (ushort*)(w + 17 * MB / 2);   // 2 MB
    ushort* Wt   = (ushort*)(w + 21 * MB / 2);   // 16 MB
    float2* part = (float2*)(w + 28 * MB);       // 8 MB

    hipMemsetAsync(loss, 0, sizeof(float), stream);
    k_pre<<<12288, 256, 0, stream>>>(lmW, Wq, Wk, Wv, idx, tok, pos, Wt, Wt3, xb);
    k_qkv_mm<<<dim3(NROWS / 128, EMB / 128, 3), 256, 0, stream>>>(xb, Wt3, qb, kbf, vt);
    k_attn<<<32, 512, 0, stream>>>(qb, kbf, vt, ao);
    k_gemm<<<8000, 256, 0, stream>>>(ao, Wt, lmb, logits, part);
    k_reduce<<<NROWS, 256, 0, stream>>>(part, logits, targets, loss);
}